// Round 4
// baseline (233.745 us; speedup 1.0000x reference)
//
#include <hip/hip_runtime.h>
#include <cstdint>

// NNLS PGD step (all tensors FLOAT32, k int32):
//   new_X = relu(th1 @ Y + weight); Y_new = new_X + (k-1)/(k+2)*(new_X - X_old)
// out (f32) = [Y_new (KB) | new_X (KB) | k+1 (1) | weight (KB)].
//
// R4:
//  - K-loop rebuilt as a 3-deep pipeline: raw s_barrier + counted
//    s_waitcnt vmcnt(6) (never 0 in steady state). Tile kt+2 issued at iter
//    kt -> every global_load_lds has ~2 iterations to land; the per-iter
//    vmcnt(0) drain of __syncthreads (R2/R3's exposed-latency bug) is gone.
//  - conv: 8B/lane float2 loads (2 columns/thread, shared slot-perm),
//    128B contiguous stores per thread.
//  - Swizzled workspace layout unchanged from R3 (bank conflicts stay ~0).

#define KDIM 1024
#define NDIM 8192
#define KB_ELEMS (1024UL * 8192UL)
#define YT_BYTES (8192UL * 1024UL * 2UL) /* 16 MiB */
#define AB_BYTES (1024UL * 1024UL * 2UL) /*  2 MiB */
#define WS_NEED (YT_BYTES + AB_BYTES)

typedef short short8 __attribute__((ext_vector_type(8)));
typedef float f32x4 __attribute__((ext_vector_type(4)));

struct __attribute__((aligned(4))) f4u { float x, y, z, w; };  // 4B-aligned 16B store

__device__ __forceinline__ uint32_t pk2(float a, float b) {
  uint32_t ua = __builtin_bit_cast(uint32_t, a) + 0x8000u;
  uint32_t ub = __builtin_bit_cast(uint32_t, b) + 0x8000u;
  return (ua >> 16) | (ub & 0xFFFF0000u);
}

__device__ __forceinline__ void ldsload16(const void* g, void* l) {
  __builtin_amdgcn_global_load_lds(
      (const __attribute__((address_space(1))) uint32_t*)g,
      (__attribute__((address_space(3))) uint32_t*)l, 16, 0, 0);
}

// ---------------- K1: convert into swizzled bf16 workspace ----------------
// blocks 0..511:  Y -> Yt[kt][n][32] bf16 (2 cols/thread, float2 loads),
//                 16B slots permuted by (n>>1)&3 (shared by the col pair)
// blocks 512..639: th1 -> A[kt][m][32] bf16, slots permuted by (m>>1)&3
__global__ __launch_bounds__(256) void nnls_conv(
    const float* __restrict__ th1, const float* __restrict__ Y,
    char* __restrict__ ws)
{
  unsigned short* yt  = (unsigned short*)ws;
  unsigned short* abf = (unsigned short*)(ws + YT_BYTES);
  const int tid = threadIdx.x;
  if (blockIdx.x < 512) {
    const int kt = blockIdx.x >> 4;                  // 0..31
    const int n  = (blockIdx.x & 15) * 512 + tid * 2;  // even
    const float* src = Y + (size_t)kt * 32 * NDIM + n;
    float2 v[32];
#pragma unroll
    for (int r = 0; r < 32; ++r) v[r] = *(const float2*)&src[(size_t)r * NDIM];
    __attribute__((aligned(16))) uint32_t oA[16], oB[16];
#pragma unroll
    for (int r = 0; r < 16; ++r) {
      oA[r] = pk2(v[2 * r].x, v[2 * r + 1].x);
      oB[r] = pk2(v[2 * r].y, v[2 * r + 1].y);
    }
    const int perm = (n >> 1) & 3;   // n even -> n and n+1 share the same perm
    uint4* dst = (uint4*)(yt + ((size_t)kt * NDIM + n) * 32);  // 128B/thread
    const uint4* a4 = (const uint4*)oA;
    const uint4* b4 = (const uint4*)oB;
#pragma unroll
    for (int q = 0; q < 4; ++q) dst[q ^ perm] = a4[q];
#pragma unroll
    for (int q = 0; q < 4; ++q) dst[4 + (q ^ perm)] = b4[q];
  } else {
    const int id = (blockIdx.x - 512) * 256 + tid;  // 0..32767
    const int kt = id >> 10, m = id & 1023;         // lanes: m consecutive
    const float4* s4 = (const float4*)(th1 + (size_t)m * KDIM + kt * 32);
    __attribute__((aligned(16))) uint32_t o[16];
#pragma unroll
    for (int q = 0; q < 8; ++q) {
      const float4 v = s4[q];
      o[2 * q]     = pk2(v.x, v.y);
      o[2 * q + 1] = pk2(v.z, v.w);
    }
    const int perm = (m >> 1) & 3;
    uint4* dst = (uint4*)(abf + ((size_t)kt * KDIM + m) * 32);  // contig stores
    const uint4* o4 = (const uint4*)o;
#pragma unroll
    for (int q = 0; q < 4; ++q) dst[q ^ perm] = o4[q];
  }
}

// ---------------- K2: GEMM + fused epilogue ----------------
// 128x64 tile, 128 thr = 2 waves (m-split), wave tile 64x64 (4x4 MFMA).
// grid (8192/64, 1024/128) = 1024 blocks -> 4 blocks/CU.
// 3-deep LDS pipeline, counted vmcnt, raw barriers.
__global__ __launch_bounds__(128, 2) void nnls_gemm4(
    const char* __restrict__ ws, const float* __restrict__ xold,
    const int* __restrict__ kin, const float* __restrict__ weight,
    float* __restrict__ out)
{
  const char* yt = ws;
  const char* ab = ws + YT_BYTES;
  __shared__ __align__(16) char smem[36864];
  // buf p @ p*12288: As (8KB: 128 rows x 64B) | Bs (4KB: 64 rows x 64B)

  const int tid  = threadIdx.x;
  const int lane = tid & 63;
  const int w    = tid >> 6;            // 0..1 (m-half of the tile)
  const int quad = lane >> 4, nl = lane & 15;

  const int m0 = blockIdx.y * 128;
  const int n0 = blockIdx.x * 64;

  // staging: per-lane = wave-uniform base + lane*16 (1KB contiguous per instr)
  const char* ag = ab + (size_t)m0 * 64 + w * 4096 + lane * 16;
  const char* bg = yt + (size_t)n0 * 64 + w * 2048 + lane * 16;

  // stage tile kt into buffer buf: 6 DMA instrs per wave (4 A + 2 B)
  auto stage = [&](int kt, int buf) {
    const char* a2 = ag + (size_t)kt * 65536;   // A kt-tile = 1024*64B
    const char* b2 = bg + (size_t)kt * 524288;  // Y kt-tile = 8192*64B
    char* d = smem + buf * 12288;
#pragma unroll
    for (int q = 0; q < 4; ++q) ldsload16(a2 + q * 1024, d + w * 4096 + q * 1024);
#pragma unroll
    for (int q = 0; q < 2; ++q) ldsload16(b2 + q * 1024, d + 8192 + w * 2048 + q * 1024);
  };

  stage(0, 0);   // prologue: tiles 0,1 in flight (12 outstanding/wave)
  stage(1, 1);

  f32x4 acc[4][4] = {};
  // swizzled frag slot: physical 16B slot = quad ^ ((row>>1)&3); row=..16k+nl
  const int fro = (quad ^ ((nl >> 1) & 3)) * 8;  // ushort offset

#pragma unroll
  for (int kt = 0; kt < 32; ++kt) {
    // wait: my 6 tile-kt loads complete; tile-kt+1's (<=6) stay in flight
    if (kt == 31) { asm volatile("s_waitcnt vmcnt(0)" ::: "memory"); }
    else          { asm volatile("s_waitcnt vmcnt(6)" ::: "memory"); }
    __builtin_amdgcn_s_barrier();  // all waves' tile-kt data now in LDS;
                                   // also fences iter kt-1 reads of buf[(kt+2)%3]
    if (kt < 30) stage(kt + 2, (kt + 2) % 3);

    const unsigned short* Asp = (const unsigned short*)(smem + (kt % 3) * 12288);
    const unsigned short* Bsp = Asp + 4096;  // +8192 B
    short8 af[4], bf[4];
#pragma unroll
    for (int i = 0; i < 4; ++i)
      af[i] = *(const short8*)&Asp[(w * 64 + i * 16 + nl) * 32 + fro];
#pragma unroll
    for (int j = 0; j < 4; ++j)
      bf[j] = *(const short8*)&Bsp[(j * 16 + nl) * 32 + fro];
#pragma unroll
    for (int i = 0; i < 4; ++i)
#pragma unroll
      for (int j = 0; j < 4; ++j)
        acc[i][j] = __builtin_amdgcn_mfma_f32_16x16x32_bf16(af[i], bf[j], acc[i][j], 0, 0, 0);
  }

  // ---- epilogue: wave-private LDS transpose -> contiguous float4 I/O ----
  // ep lives in buf0 region (<=9216B); last K-step read buf1 (31%3==1) and all
  // DMAs drained (vmcnt(0) at iter 31) -> no barrier needed.
  const float kf  = (float)kin[0];
  const float mom = (kf - 1.0f) / (kf + 2.0f);
  float* ep = (float*)(smem + w * 4608);  // 16 rows x 68 f32 (pad) per wave
  const int u  = lane >> 4;               // read row-in-group 0..3
  const int cq = lane & 15;               // read col quad (x4 floats)

#pragma unroll
  for (int i = 0; i < 4; ++i) {
    const int mgb = m0 + w * 64 + i * 16;
    // hoist the chunk's global loads ahead of the LDS scatter (8KB in flight)
    size_t idxs[4]; float4 wv[4], xo[4];
#pragma unroll
    for (int t = 0; t < 4; ++t) {
      idxs[t] = (size_t)(mgb + t * 4 + u) * NDIM + n0 + cq * 4;
      wv[t] = *(const float4*)&weight[idxs[t]];
      xo[t] = *(const float4*)&xold[idxs[t]];
    }
    // scatter acc chunk i (16 rows x 64 cols); stride 68 -> 2-way writes (free)
#pragma unroll
    for (int j = 0; j < 4; ++j)
#pragma unroll
      for (int r = 0; r < 4; ++r)
        ep[(quad * 4 + r) * 68 + j * 16 + nl] = acc[i][j][r];
    // no barrier: ep wave-private; same-wave DS ops are in-order
#pragma unroll
    for (int t = 0; t < 4; ++t) {
      const float4 cv = *(const float4*)&ep[(t * 4 + u) * 68 + cq * 4];
      const size_t idx = idxs[t];  // 4 rows x 256B contiguous runs per instr
      float4 nx, yn;
      nx.x = fmaxf(cv.x + wv[t].x, 0.0f); nx.y = fmaxf(cv.y + wv[t].y, 0.0f);
      nx.z = fmaxf(cv.z + wv[t].z, 0.0f); nx.w = fmaxf(cv.w + wv[t].w, 0.0f);
      yn.x = nx.x + mom * (nx.x - xo[t].x); yn.y = nx.y + mom * (nx.y - xo[t].y);
      yn.z = nx.z + mom * (nx.z - xo[t].z); yn.w = nx.w + mom * (nx.w - xo[t].w);
      *(float4*)&out[idx] = yn;               // Y_new (16B aligned)
      *(float4*)&out[KB_ELEMS + idx] = nx;    // new_X (16B aligned)
      f4u s; s.x = wv[t].x; s.y = wv[t].y; s.z = wv[t].z; s.w = wv[t].w;
      *(f4u*)&out[2 * KB_ELEMS + 1 + idx] = s;  // weight passthrough (4B aligned)
    }
  }

  if (blockIdx.x == 0 && blockIdx.y == 0 && tid == 0)
    out[2 * KB_ELEMS] = (float)(kin[0] + 1);
}

// ---------------- fallback: single-kernel path (ws too small) ----------------
#define LDA 40
__global__ __launch_bounds__(512, 4) void nnls_gemm_v1(
    const float* __restrict__ th1, const float* __restrict__ Y,
    const float* __restrict__ xold, const int* __restrict__ kin,
    const float* __restrict__ weight, float* __restrict__ out)
{
  __shared__ __align__(16) char smem[40960];
  unsigned short* As0 = (unsigned short*)smem;
  unsigned short* Bs0 = (unsigned short*)(smem + 10240);
  unsigned short* As1 = (unsigned short*)(smem + 20480);
  unsigned short* Bs1 = (unsigned short*)(smem + 30720);

  const int tid  = threadIdx.x;
  const int lane = tid & 63;
  const int w    = tid >> 6;
  const int wm = w >> 1, wn = w & 1;
  const int quad = lane >> 4, nl = lane & 15;
  const int m0 = blockIdx.y * 128;
  const int n0 = blockIdx.x * 128;
  const int ar = tid >> 3;
  const int ac = tid & 7;
  const float* abase = th1 + (size_t)(m0 + ar) * KDIM + ac * 4;
  const int bn = tid & 127;
  const int bk = (tid >> 7) * 8;
  const float* ybase = Y + (size_t)bk * NDIM + n0 + bn;

  float4 abv[2];
  float  yb[8];
  abv[0] = *(const float4*)(abase);
  abv[1] = *(const float4*)(abase + (size_t)64 * KDIM);
#pragma unroll
  for (int r = 0; r < 8; ++r) yb[r] = ybase[(size_t)r * NDIM];

  f32x4 acc[2][4] = {};

#pragma unroll 2
  for (int kt = 0; kt < 32; ++kt) {
    unsigned short* Asp = (kt & 1) ? As1 : As0;
    unsigned short* Bsp = (kt & 1) ? Bs1 : Bs0;
    {
      uint2 d0; d0.x = pk2(abv[0].x, abv[0].y); d0.y = pk2(abv[0].z, abv[0].w);
      *(uint2*)&Asp[ar * LDA + ac * 4] = d0;
      uint2 d1; d1.x = pk2(abv[1].x, abv[1].y); d1.y = pk2(abv[1].z, abv[1].w);
      *(uint2*)&Asp[(ar + 64) * LDA + ac * 4] = d1;
      uint4 e;
      e.x = pk2(yb[0], yb[1]); e.y = pk2(yb[2], yb[3]);
      e.z = pk2(yb[4], yb[5]); e.w = pk2(yb[6], yb[7]);
      *(uint4*)&Bsp[bn * LDA + bk] = e;
    }
    __syncthreads();
    if (kt < 31) {
      const float* an = abase + (kt + 1) * 32;
      abv[0] = *(const float4*)(an);
      abv[1] = *(const float4*)(an + (size_t)64 * KDIM);
      const float* yn = ybase + (size_t)((kt + 1) * 32) * NDIM;
#pragma unroll
      for (int r = 0; r < 8; ++r) yb[r] = yn[(size_t)r * NDIM];
    }
    short8 af[2], bf[4];
#pragma unroll
    for (int i = 0; i < 2; ++i)
      af[i] = *(const short8*)&Asp[(wm * 32 + i * 16 + nl) * LDA + quad * 8];
#pragma unroll
    for (int j = 0; j < 4; ++j)
      bf[j] = *(const short8*)&Bsp[(wn * 64 + j * 16 + nl) * LDA + quad * 8];
#pragma unroll
    for (int i = 0; i < 2; ++i)
#pragma unroll
      for (int j = 0; j < 4; ++j)
        acc[i][j] = __builtin_amdgcn_mfma_f32_16x16x32_bf16(af[i], bf[j], acc[i][j], 0, 0, 0);
    __syncthreads();
  }
  __syncthreads();

  const float kf  = (float)kin[0];
  const float mom = (kf - 1.0f) / (kf + 2.0f);
  float* ep = (float*)smem + w * 1088;
  const int u  = lane >> 4;
  const int mc = lane & 15;
#pragma unroll
  for (int i = 0; i < 2; ++i) {
#pragma unroll
    for (int j = 0; j < 4; ++j)
#pragma unroll
      for (int r = 0; r < 4; ++r)
        ep[(quad * 4 + r) * 68 + (j * 16 + nl)] = acc[i][j][r];
    const int mgb = m0 + wm * 32 + i * 16;
#pragma unroll
    for (int t = 0; t < 4; ++t) {
      const int row = t * 4 + u;
      const float4 cv = *(const float4*)&ep[row * 68 + mc * 4];
      const int ng = n0 + wn * 64 + mc * 4;
      const size_t idx = (size_t)(mgb + row) * NDIM + ng;
      const float4 wv = *(const float4*)&weight[idx];
      const float4 xo = *(const float4*)&xold[idx];
      float4 nx, yn;
      nx.x = fmaxf(cv.x + wv.x, 0.0f); nx.y = fmaxf(cv.y + wv.y, 0.0f);
      nx.z = fmaxf(cv.z + wv.z, 0.0f); nx.w = fmaxf(cv.w + wv.w, 0.0f);
      yn.x = nx.x + mom * (nx.x - xo.x); yn.y = nx.y + mom * (nx.y - xo.y);
      yn.z = nx.z + mom * (nx.z - xo.z); yn.w = nx.w + mom * (nx.w - xo.w);
      *(float4*)&out[idx] = yn;
      *(float4*)&out[KB_ELEMS + idx] = nx;
      f4u s; s.x = wv.x; s.y = wv.y; s.z = wv.z; s.w = wv.w;
      *(f4u*)&out[2 * KB_ELEMS + 1 + idx] = s;
    }
  }
  if (blockIdx.x == 0 && blockIdx.y == 0 && tid == 0)
    out[2 * KB_ELEMS] = (float)(kin[0] + 1);
}

extern "C" void kernel_launch(void* const* d_in, const int* in_sizes, int n_in,
                              void* d_out, int out_size, void* d_ws, size_t ws_size,
                              hipStream_t stream) {
  const float* th1  = (const float*)d_in[0];
  const float* Y    = (const float*)d_in[1];
  const float* xold = (const float*)d_in[2];
  const int*   kin  = (const int*)d_in[3];
  const float* wgt  = (const float*)d_in[4];
  float* out = (float*)d_out;

  if (d_ws != nullptr && ws_size >= WS_NEED) {
    nnls_conv<<<640, 256, 0, stream>>>(th1, Y, (char*)d_ws);
    nnls_gemm4<<<dim3(NDIM / 64, KDIM / 128), 128, 0, stream>>>(
        (const char*)d_ws, xold, kin, wgt, out);
  } else {
    nnls_gemm_v1<<<dim3(NDIM / 128, KDIM / 128), 512, 0, stream>>>(
        th1, Y, xold, kin, wgt, out);
  }
}

// Round 5
// 225.657 us; speedup vs baseline: 1.0358x; 1.0358x over previous
//
#include <hip/hip_runtime.h>
#include <cstdint>

// NNLS PGD step (all tensors FLOAT32, k int32):
//   new_X = relu(th1 @ Y + weight); Y_new = new_X + (k-1)/(k+2)*(new_X - X_old)
// out (f32) = [Y_new (KB) | new_X (KB) | k+1 (1) | weight (KB)].
//
// R5:
//  - gemm: 4 waves/block (was 2) with the SAME conflict-free swizzled layout
//    AND the 3-deep counted-vmcnt pipeline. 4 blocks/CU x 4 waves = 16
//    waves/CU (2x R4). stage = 3 DMA/thread -> vmcnt(3) steady state.
//    Wave tile 64x32 (acc[4][2]), 8 MFMA + 6 ds_read_b128 per wave per iter.
//  - conv: reverted to R3's 1152-block version (R4's 640-block variant
//    regressed ~+8us).

#define KDIM 1024
#define NDIM 8192
#define KB_ELEMS (1024UL * 8192UL)
#define YT_BYTES (8192UL * 1024UL * 2UL) /* 16 MiB */
#define AB_BYTES (1024UL * 1024UL * 2UL) /*  2 MiB */
#define WS_NEED (YT_BYTES + AB_BYTES)

typedef short short8 __attribute__((ext_vector_type(8)));
typedef float f32x4 __attribute__((ext_vector_type(4)));

struct __attribute__((aligned(4))) f4u { float x, y, z, w; };  // 4B-aligned 16B store

__device__ __forceinline__ uint32_t pk2(float a, float b) {
  uint32_t ua = __builtin_bit_cast(uint32_t, a) + 0x8000u;
  uint32_t ub = __builtin_bit_cast(uint32_t, b) + 0x8000u;
  return (ua >> 16) | (ub & 0xFFFF0000u);
}

__device__ __forceinline__ void ldsload16(const void* g, void* l) {
  __builtin_amdgcn_global_load_lds(
      (const __attribute__((address_space(1))) uint32_t*)g,
      (__attribute__((address_space(3))) uint32_t*)l, 16, 0, 0);
}

// ---------------- K1: convert into swizzled bf16 workspace ----------------
// blocks 0..1023:   Y -> Yt[kt][n][32] bf16, 16B slots permuted by (n>>1)&3
// blocks 1024..1151: th1 -> A[kt][m][32] bf16, slots permuted by (m>>1)&3
__global__ __launch_bounds__(256) void nnls_conv(
    const float* __restrict__ th1, const float* __restrict__ Y,
    char* __restrict__ ws)
{
  unsigned short* yt  = (unsigned short*)ws;
  unsigned short* abf = (unsigned short*)(ws + YT_BYTES);
  const int tid = threadIdx.x;
  if (blockIdx.x < 1024) {
    const int kt = blockIdx.x >> 5;            // 0..31
    const int n  = (blockIdx.x & 31) * 256 + tid;
    const float* src = Y + (size_t)kt * 32 * NDIM + n;  // lanes: n consecutive
    float v[32];
#pragma unroll
    for (int r = 0; r < 32; ++r) v[r] = src[(size_t)r * NDIM];
    __attribute__((aligned(16))) uint32_t o[16];
#pragma unroll
    for (int r = 0; r < 16; ++r) o[r] = pk2(v[2 * r], v[2 * r + 1]);
    const int perm = (n >> 1) & 3;
    uint4* dst = (uint4*)(yt + ((size_t)kt * NDIM + n) * 32);  // 64B/thread, contig
    const uint4* o4 = (const uint4*)o;
#pragma unroll
    for (int q = 0; q < 4; ++q) dst[q ^ perm] = o4[q];
  } else {
    const int id = (blockIdx.x - 1024) * 256 + tid;  // 0..32767
    const int kt = id >> 10, m = id & 1023;          // lanes: m consecutive
    const float4* s4 = (const float4*)(th1 + (size_t)m * KDIM + kt * 32);
    __attribute__((aligned(16))) uint32_t o[16];
#pragma unroll
    for (int q = 0; q < 8; ++q) {
      const float4 v = s4[q];
      o[2 * q]     = pk2(v.x, v.y);
      o[2 * q + 1] = pk2(v.z, v.w);
    }
    const int perm = (m >> 1) & 3;
    uint4* dst = (uint4*)(abf + ((size_t)kt * KDIM + m) * 32);  // contig stores
    const uint4* o4 = (const uint4*)o;
#pragma unroll
    for (int q = 0; q < 4; ++q) dst[q ^ perm] = o4[q];
  }
}

// ---------------- K2: GEMM + fused epilogue ----------------
// 128x64 tile, 256 thr = 4 waves (2m x 2n), wave tile 64x32 (4x2 MFMA).
// grid (8192/64, 1024/128) = 1024 blocks -> 4 blocks/CU, 16 waves/CU.
// 3-deep LDS pipeline, counted vmcnt(3), raw barriers.
__global__ __launch_bounds__(256, 4) void nnls_gemm5(
    const char* __restrict__ ws, const float* __restrict__ xold,
    const int* __restrict__ kin, const float* __restrict__ weight,
    float* __restrict__ out)
{
  const char* yt = ws;
  const char* ab = ws + YT_BYTES;
  __shared__ __align__(16) char smem[36864];
  // buf p @ p*12288: As (8KB: 128 rows x 64B) | Bs (4KB: 64 rows x 64B)

  const int tid  = threadIdx.x;
  const int lane = tid & 63;
  const int w    = tid >> 6;            // 0..3
  const int wm = w >> 1, wn = w & 1;    // 2m x 2n wave grid
  const int quad = lane >> 4, nl = lane & 15;

  const int m0 = blockIdx.y * 128;
  const int n0 = blockIdx.x * 64;

  // staging sources: per-lane = wave-uniform base + lane*16 (1KB/instr)
  const char* ag = ab + (size_t)m0 * 64 + w * 1024 + lane * 16;
  const char* bg = yt + (size_t)n0 * 64 + w * 1024 + lane * 16;

  // stage tile kt into buffer buf: 3 DMA instrs per thread (2 A + 1 B)
  auto stage = [&](int kt, int buf) {
    const char* a2 = ag + (size_t)kt * 65536;   // A kt-tile = 1024*64B
    const char* b2 = bg + (size_t)kt * 524288;  // Y kt-tile = 8192*64B
    char* d = smem + buf * 12288;
    ldsload16(a2,        d + w * 1024);
    ldsload16(a2 + 4096, d + 4096 + w * 1024);
    ldsload16(b2,        d + 8192 + w * 1024);
  };

  stage(0, 0);   // prologue: tiles 0,1 in flight (6 outstanding/wave)
  stage(1, 1);

  f32x4 acc[4][2] = {};
  // swizzled frag slot: physical 16B slot = quad ^ ((row>>1)&3); row=..16c+nl
  const int fro = (quad ^ ((nl >> 1) & 3)) * 8;  // ushort offset

#pragma unroll
  for (int kt = 0; kt < 32; ++kt) {
    // wait: my 3 tile-kt loads complete; tile-kt+1's (<=3) stay in flight
    if (kt == 31) { asm volatile("s_waitcnt vmcnt(0)" ::: "memory"); }
    else          { asm volatile("s_waitcnt vmcnt(3)" ::: "memory"); }
    __builtin_amdgcn_s_barrier();  // all waves' tile-kt data now in LDS;
                                   // also fences iter kt-1 reads of buf[(kt+2)%3]
    if (kt < 30) stage(kt + 2, (kt + 2) % 3);

    const unsigned short* Asp = (const unsigned short*)(smem + (kt % 3) * 12288);
    const unsigned short* Bsp = Asp + 4096;  // +8192 B
    short8 af[4], bf[2];
#pragma unroll
    for (int i = 0; i < 4; ++i)
      af[i] = *(const short8*)&Asp[(wm * 64 + i * 16 + nl) * 32 + fro];
#pragma unroll
    for (int j = 0; j < 2; ++j)
      bf[j] = *(const short8*)&Bsp[(wn * 32 + j * 16 + nl) * 32 + fro];
#pragma unroll
    for (int i = 0; i < 4; ++i)
#pragma unroll
      for (int j = 0; j < 2; ++j)
        acc[i][j] = __builtin_amdgcn_mfma_f32_16x16x32_bf16(af[i], bf[j], acc[i][j], 0, 0, 0);
  }

  // ---- epilogue: wave-private LDS transpose -> contiguous float4 I/O ----
  // ep = smem[0..9215]; all DMAs into buf0 (tile 30) drained before the
  // iter-31 barrier (each wave's vmcnt(3) at iter-30 precedes it); tile-31
  // DMAs target buf2 (disjoint). Own acc is in registers -> no barrier.
  const float kf  = (float)kin[0];
  const float mom = (kf - 1.0f) / (kf + 2.0f);
  float* ep = (float*)smem + w * 576;   // 16 rows x 36 f32 = 2304B per wave
  const int rl = lane >> 3;             // read row-in-group 0..7
  const int cc = lane & 7;              // read col quarter (x4 floats), 0..7

#pragma unroll
  for (int i = 0; i < 4; ++i) {
    const int mgb = m0 + wm * 64 + i * 16;
    // hoist the chunk's global loads ahead of the LDS scatter
    size_t idxs[2]; float4 wv[2], xo[2];
#pragma unroll
    for (int t = 0; t < 2; ++t) {
      idxs[t] = (size_t)(mgb + t * 8 + rl) * NDIM + n0 + wn * 32 + cc * 4;
      wv[t] = *(const float4*)&weight[idxs[t]];
      xo[t] = *(const float4*)&xold[idxs[t]];
    }
    // scatter acc chunk i (16 rows x 32 cols); stride 36 -> 2-way writes (free)
#pragma unroll
    for (int j = 0; j < 2; ++j)
#pragma unroll
      for (int r = 0; r < 4; ++r)
        ep[(quad * 4 + r) * 36 + j * 16 + nl] = acc[i][j][r];
    // no barrier: ep wave-private; same-wave DS ops are in-order
#pragma unroll
    for (int t = 0; t < 2; ++t) {
      const float4 cv = *(const float4*)&ep[(t * 8 + rl) * 36 + cc * 4];
      const size_t idx = idxs[t];  // 8 rows x 128B contiguous runs per instr
      float4 nx, yn;
      nx.x = fmaxf(cv.x + wv[t].x, 0.0f); nx.y = fmaxf(cv.y + wv[t].y, 0.0f);
      nx.z = fmaxf(cv.z + wv[t].z, 0.0f); nx.w = fmaxf(cv.w + wv[t].w, 0.0f);
      yn.x = nx.x + mom * (nx.x - xo[t].x); yn.y = nx.y + mom * (nx.y - xo[t].y);
      yn.z = nx.z + mom * (nx.z - xo[t].z); yn.w = nx.w + mom * (nx.w - xo[t].w);
      *(float4*)&out[idx] = yn;               // Y_new (16B aligned)
      *(float4*)&out[KB_ELEMS + idx] = nx;    // new_X (16B aligned)
      f4u s; s.x = wv[t].x; s.y = wv[t].y; s.z = wv[t].z; s.w = wv[t].w;
      *(f4u*)&out[2 * KB_ELEMS + 1 + idx] = s;  // weight passthrough (4B aligned)
    }
  }

  if (blockIdx.x == 0 && blockIdx.y == 0 && tid == 0)
    out[2 * KB_ELEMS] = (float)(kin[0] + 1);
}

// ---------------- fallback: single-kernel path (ws too small) ----------------
#define LDA 40
__global__ __launch_bounds__(512, 4) void nnls_gemm_v1(
    const float* __restrict__ th1, const float* __restrict__ Y,
    const float* __restrict__ xold, const int* __restrict__ kin,
    const float* __restrict__ weight, float* __restrict__ out)
{
  __shared__ __align__(16) char smem[40960];
  unsigned short* As0 = (unsigned short*)smem;
  unsigned short* Bs0 = (unsigned short*)(smem + 10240);
  unsigned short* As1 = (unsigned short*)(smem + 20480);
  unsigned short* Bs1 = (unsigned short*)(smem + 30720);

  const int tid  = threadIdx.x;
  const int lane = tid & 63;
  const int w    = tid >> 6;
  const int wm = w >> 1, wn = w & 1;
  const int quad = lane >> 4, nl = lane & 15;
  const int m0 = blockIdx.y * 128;
  const int n0 = blockIdx.x * 128;
  const int ar = tid >> 3;
  const int ac = tid & 7;
  const float* abase = th1 + (size_t)(m0 + ar) * KDIM + ac * 4;
  const int bn = tid & 127;
  const int bk = (tid >> 7) * 8;
  const float* ybase = Y + (size_t)bk * NDIM + n0 + bn;

  float4 abv[2];
  float  yb[8];
  abv[0] = *(const float4*)(abase);
  abv[1] = *(const float4*)(abase + (size_t)64 * KDIM);
#pragma unroll
  for (int r = 0; r < 8; ++r) yb[r] = ybase[(size_t)r * NDIM];

  f32x4 acc[2][4] = {};

#pragma unroll 2
  for (int kt = 0; kt < 32; ++kt) {
    unsigned short* Asp = (kt & 1) ? As1 : As0;
    unsigned short* Bsp = (kt & 1) ? Bs1 : Bs0;
    {
      uint2 d0; d0.x = pk2(abv[0].x, abv[0].y); d0.y = pk2(abv[0].z, abv[0].w);
      *(uint2*)&Asp[ar * LDA + ac * 4] = d0;
      uint2 d1; d1.x = pk2(abv[1].x, abv[1].y); d1.y = pk2(abv[1].z, abv[1].w);
      *(uint2*)&Asp[(ar + 64) * LDA + ac * 4] = d1;
      uint4 e;
      e.x = pk2(yb[0], yb[1]); e.y = pk2(yb[2], yb[3]);
      e.z = pk2(yb[4], yb[5]); e.w = pk2(yb[6], yb[7]);
      *(uint4*)&Bsp[bn * LDA + bk] = e;
    }
    __syncthreads();
    if (kt < 31) {
      const float* an = abase + (kt + 1) * 32;
      abv[0] = *(const float4*)(an);
      abv[1] = *(const float4*)(an + (size_t)64 * KDIM);
      const float* yn = ybase + (size_t)((kt + 1) * 32) * NDIM;
#pragma unroll
      for (int r = 0; r < 8; ++r) yb[r] = yn[(size_t)r * NDIM];
    }
    short8 af[2], bf[4];
#pragma unroll
    for (int i = 0; i < 2; ++i)
      af[i] = *(const short8*)&Asp[(wm * 32 + i * 16 + nl) * LDA + quad * 8];
#pragma unroll
    for (int j = 0; j < 4; ++j)
      bf[j] = *(const short8*)&Bsp[(wn * 64 + j * 16 + nl) * LDA + quad * 8];
#pragma unroll
    for (int i = 0; i < 2; ++i)
#pragma unroll
      for (int j = 0; j < 4; ++j)
        acc[i][j] = __builtin_amdgcn_mfma_f32_16x16x32_bf16(af[i], bf[j], acc[i][j], 0, 0, 0);
    __syncthreads();
  }
  __syncthreads();

  const float kf  = (float)kin[0];
  const float mom = (kf - 1.0f) / (kf + 2.0f);
  float* ep = (float*)smem + w * 1088;
  const int u  = lane >> 4;
  const int mc = lane & 15;
#pragma unroll
  for (int i = 0; i < 2; ++i) {
#pragma unroll
    for (int j = 0; j < 4; ++j)
#pragma unroll
      for (int r = 0; r < 4; ++r)
        ep[(quad * 4 + r) * 68 + (j * 16 + nl)] = acc[i][j][r];
    const int mgb = m0 + wm * 32 + i * 16;
#pragma unroll
    for (int t = 0; t < 4; ++t) {
      const int row = t * 4 + u;
      const float4 cv = *(const float4*)&ep[row * 68 + mc * 4];
      const int ng = n0 + wn * 64 + mc * 4;
      const size_t idx = (size_t)(mgb + row) * NDIM + ng;
      const float4 wv = *(const float4*)&weight[idx];
      const float4 xo = *(const float4*)&xold[idx];
      float4 nx, yn;
      nx.x = fmaxf(cv.x + wv.x, 0.0f); nx.y = fmaxf(cv.y + wv.y, 0.0f);
      nx.z = fmaxf(cv.z + wv.z, 0.0f); nx.w = fmaxf(cv.w + wv.w, 0.0f);
      yn.x = nx.x + mom * (nx.x - xo.x); yn.y = nx.y + mom * (nx.y - xo.y);
      yn.z = nx.z + mom * (nx.z - xo.z); yn.w = nx.w + mom * (nx.w - xo.w);
      *(float4*)&out[idx] = yn;
      *(float4*)&out[KB_ELEMS + idx] = nx;
      f4u s; s.x = wv.x; s.y = wv.y; s.z = wv.z; s.w = wv.w;
      *(f4u*)&out[2 * KB_ELEMS + 1 + idx] = s;
    }
  }
  if (blockIdx.x == 0 && blockIdx.y == 0 && tid == 0)
    out[2 * KB_ELEMS] = (float)(kin[0] + 1);
}

extern "C" void kernel_launch(void* const* d_in, const int* in_sizes, int n_in,
                              void* d_out, int out_size, void* d_ws, size_t ws_size,
                              hipStream_t stream) {
  const float* th1  = (const float*)d_in[0];
  const float* Y    = (const float*)d_in[1];
  const float* xold = (const float*)d_in[2];
  const int*   kin  = (const int*)d_in[3];
  const float* wgt  = (const float*)d_in[4];
  float* out = (float*)d_out;

  if (d_ws != nullptr && ws_size >= WS_NEED) {
    nnls_conv<<<1152, 256, 0, stream>>>(th1, Y, (char*)d_ws);
    nnls_gemm5<<<dim3(NDIM / 64, KDIM / 128), 256, 0, stream>>>(
        (const char*)d_ws, xold, kin, wgt, out);
  } else {
    nnls_gemm_v1<<<dim3(NDIM / 128, KDIM / 128), 512, 0, stream>>>(
        th1, Y, xold, kin, wgt, out);
  }
}